// Round 13
// baseline (471.868 us; speedup 1.0000x reference)
//
#include <hip/hip_runtime.h>

typedef __attribute__((ext_vector_type(8))) short short8;
typedef __attribute__((ext_vector_type(4))) float f32x4;

#define SEQ 2048
#define BATCH 64
#define HID 512
#define ATT 512

__device__ __forceinline__ unsigned short f2bf(float f) {
  unsigned u = __float_as_uint(f);
  u += 0x7fffu + ((u >> 16) & 1u);   // round-to-nearest-even
  return (unsigned short)(u >> 16);
}

// 8 fp32 -> 8 bf16 (RNE) in 4 VALU ops via v_cvt_pk_bf16_f32.
// NOTE: lo/hi are f32x4 (ext_vector), NOT HIP float4 (struct) — ext_vector is a
// first-class register value, required for the tied "+v" asm operands below
// (clang: "tied indirect register inputs" error on struct operands).
__device__ __forceinline__ short8 cvt8(f32x4 lo, f32x4 hi) {
  union { unsigned u[4]; short8 s; } r;
  asm("v_cvt_pk_bf16_f32 %0, %1, %2" : "=v"(r.u[0]) : "v"(lo.x), "v"(lo.y));
  asm("v_cvt_pk_bf16_f32 %0, %1, %2" : "=v"(r.u[1]) : "v"(lo.z), "v"(lo.w));
  asm("v_cvt_pk_bf16_f32 %0, %1, %2" : "=v"(r.u[2]) : "v"(hi.x), "v"(hi.y));
  asm("v_cvt_pk_bf16_f32 %0, %1, %2" : "=v"(r.u[3]) : "v"(hi.z), "v"(hi.w));
  return r.s;
}

// B-frag load straight to registers: uniform SGPR base + per-lane 32b voffset.
#define GLOADS(dst, voff, base, OFF) \
  asm volatile("global_load_dwordx4 %0, %1, %2 offset:" #OFF \
               : "=v"(dst) : "v"(voff), "s"(base))

// Counted vmcnt waits; "+v" re-defines the live regs at the wait so consumers
// data-depend on it (rule-18 fence without sched_barrier). All tied operands
// are ext_vector types (short8 / f32x4) — struct types do NOT compile here.
#define BWAIT(N, b0, b1, b2, b3) \
  asm volatile("s_waitcnt vmcnt(" #N ")" \
               : "+v"(b0), "+v"(b1), "+v"(b2), "+v"(b3) :: "memory")
#define AWAIT(N, a0, a1) \
  asm volatile("s_waitcnt vmcnt(" #N ")" \
               : "+v"(a0), "+v"(a1) :: "memory")

// Hand-asm LDS ops (no compiler-scoreboard interference). IMM constant-folds.
#define DSREADS(dst, vaddr, IMM) \
  asm volatile("ds_read_b128 %0, %1 offset:%2" \
               : "=v"(dst) : "v"(vaddr), "i"(IMM))
#define DSWRITE(vaddr, data, IMM) \
  asm volatile("ds_write_b128 %0, %1 offset:%2" \
               :: "v"(vaddr), "v"(data), "i"(IMM) : "memory")

// A-stage global load: 2 dwordx4 (32B fp32 = 8 consecutive k) per thread.
#define ALOAD(set, tt) do { \
    unsigned va_ = voffA + (unsigned)(tt) * 128u; \
    asm volatile("global_load_dwordx4 %0, %1, %2 offset:0"  : "=v"(aLo[set]) : "v"(va_), "s"(encB)); \
    asm volatile("global_load_dwordx4 %0, %1, %2 offset:16" : "=v"(aHi[set]) : "v"(va_), "s"(encB)); \
  } while (0)

#define LOADB(set, t_) do { \
    const unsigned short* bk_ = wsb + (size_t)(t_) * 16384; \
    GLOADS(bf[set][0], voff, bk_, 0); \
    GLOADS(bf[set][1], voff, bk_, 1024); \
    GLOADS(bf[set][2], voff, bk_, 2048); \
    GLOADS(bf[set][3], voff, bk_, 3072); \
  } while (0)

// Pre-kernel: zero out; blocks 0..63 -> decT[a][b]=(W_t@dec_out[b]+b_t)[a] (transposed);
// blocks 64..127 -> wsb = W_s bf16 image:
//   (n=a,k=h): chunk h>>5 (16384 shorts); 16B block (n>>4)*64+((h>>3)&3)*16+(n&15),
//   short idx = block*8 + (h&7).
__global__ void bahdanau_pre(const float* __restrict__ dec_out,
                             const float* __restrict__ W_t,
                             const float* __restrict__ b_t,
                             const float* __restrict__ W_s,
                             unsigned short* __restrict__ wsb,
                             float* __restrict__ decT,
                             float* __restrict__ out) {
  // zero out (64x2048 f32 = 32768 float4 = 128 blk x 256 thr)
  ((float4*)out)[blockIdx.x * 256 + threadIdx.x] = make_float4(0.f, 0.f, 0.f, 0.f);

  if (blockIdx.x < 64) {
    const int b = blockIdx.x;
    __shared__ float drow[HID];
    for (int i = threadIdx.x; i < HID; i += 256) drow[i] = dec_out[b * HID + i];
    __syncthreads();
    for (int a = threadIdx.x; a < ATT; a += 256) {
      const float4* wr = (const float4*)(W_t + (size_t)a * HID);
      float s0 = 0.f, s1 = 0.f, s2 = 0.f, s3 = 0.f;
#pragma unroll 4
      for (int j = 0; j < HID / 4; ++j) {
        float4 w = wr[j];
        s0 = fmaf(w.x, drow[4 * j + 0], s0);
        s1 = fmaf(w.y, drow[4 * j + 1], s1);
        s2 = fmaf(w.z, drow[4 * j + 2], s2);
        s3 = fmaf(w.w, drow[4 * j + 3], s3);
      }
      decT[a * BATCH + b] = (s0 + s1) + (s2 + s3) + b_t[a];
    }
  } else {
    const int cb = blockIdx.x - 64;
    const float4* src = (const float4*)W_s;
#pragma unroll
    for (int i = 0; i < 4; ++i) {
      int idx = cb * 1024 + i * 256 + threadIdx.x;
      float4 v = src[idx];
      int a = idx >> 7;
      int h = (idx & 127) * 4;
      ushort4 o;
      o.x = f2bf(v.x); o.y = f2bf(v.y); o.z = f2bf(v.z); o.w = f2bf(v.w);
      int blk = (a >> 4) * 64 + ((h >> 3) & 3) * 16 + (a & 15);
      int dst = (h >> 5) * 16384 + blk * 8 + (h & 7);
      *(ushort4*)&wsb[dst] = o;
    }
  }
}

// Main: 4096 blocks x 256 thr (4 waves), 3 blocks/CU.
//  - XCD pair-swizzle: wid=(bid&7)*512+(bid>>3); (s,h)=(wid>>1,wid&1). Both h-blocks
//    of an s land adjacent on the SAME XCD -> duplicate A-read is an L2 hit
//    (fixes the 265 MB double-fetch).
//  - A staged as BF16 (4 KB/tile): producer path global->reg (2 dwordx4/thread,
//    row=w*16+(l>>2), 32B chunk (l&3)*32) -> cvt_pk x4 -> 1 ds_write_b128
//    ([row][k] layout, 64 B row stride: bank-balanced write AND read, 8-cyc min).
//    Consumer: ONE ds_read_b128 per mt-frag (was 2 fp32 reads + cvt per frag).
//    LDS traffic per block-iter: 40 KB -> 20 KB; cvt VALU work /4.
//  - B: register loads from L2-resident wsb, depth-1 prefetch (unchanged).
//  - Ledger (in-order vmcnt), invariant at iter entry: [B(i):4, A(i+1):2].
//    Issue B(i+1)x4, A(i+2)x2 -> 12 outstanding. BWAIT(8) drains B(i);
//    AWAIT(6) drains A(i+1) -> cvt -> ds_write tile(i+1). Tails: i=14: 6/4; i=15: 0.
//  - NB=2 LDS buffers suffice: readers of tile(i-1) drained lgkm before the
//    barrier ending iter i-1; writer of tile(i+1) (same buffer) runs in iter i.
__global__ __launch_bounds__(256, 3)
void bahdanau_main(const float* __restrict__ enc,
                   const unsigned short* __restrict__ wsb,
                   const float* __restrict__ decT,
                   const float* __restrict__ v_a,
                   float* __restrict__ out) {
  __shared__ __align__(16) short Ab[2][2048];   // 2 x 4 KB bf16 A tiles
  __shared__ float partial[256];

  const int tid  = threadIdx.x;
  const int w    = tid >> 6;        // wave 0..3
  const int lane = tid & 63;
  const int c = lane & 15;
  const int q = lane >> 4;

  // XCD pair swizzle (bijective on 4096: 8 XCDs x 512 contiguous work-ids)
  const int bid = blockIdx.x;
  const int wid = (bid & 7) * 512 + (bid >> 3);
  const int s = wid >> 1;
  const int h = wid & 1;
  const int n0 = h * 256 + w * 64;
  const int t0 = (s & 7) * 2;       // stagger start tile

  const float* encB = enc + (size_t)s * 64 * HID;

  // A-stage source: thread (w,l) -> row r=w*16+(l>>2), fp32 bytes (l&3)*32 (+16)
  const unsigned voffA = (unsigned)((w * 16 + (lane >> 2)) * 2048 + (lane & 3) * 32);

  // B-frag byte offset: ((h*4+w)*256 + q*16 + c)*16 (+ nt*1024, + t*32768 via base)
  const unsigned voff = (unsigned)(((h * 4 + w) * 256 + q * 16 + c) * 16);

  // LDS as3 byte offsets: read (row=mt*16+c, kslot q); write (row=w*16+(l>>2), kslot l&3)
  const unsigned lA = (unsigned)(size_t)(__attribute__((address_space(3))) char*)&Ab[0][0];
  const unsigned rdOff = lA + (unsigned)(c * 64 + q * 16);
  const unsigned wtOff = lA + (unsigned)((w * 16 + (lane >> 2)) * 64 + (lane & 3) * 16);

  // acc init = dec_att (decT L2-warm)
  f32x4 acc[4][4];
#pragma unroll
  for (int nt = 0; nt < 4; ++nt)
#pragma unroll
    for (int mt = 0; mt < 4; ++mt)
      acc[mt][nt] = *(const f32x4*)(decT + (size_t)(n0 + nt * 16 + c) * 64 + mt * 16 + q * 4);

  asm volatile("s_waitcnt vmcnt(0)" ::: "memory");   // ledger starts clean

  short8 bf[2][4];
  f32x4 aLo[2], aHi[2];   // ext_vector (NOT float4 struct): tied asm operands

  // ---- prologue (queue order): A(0):2 | B(0):4 | A(1):2 ----
  ALOAD(0, t0);
  LOADB(0, t0);
  ALOAD(1, (t0 + 1) & 15);
  AWAIT(6, aLo[0], aHi[0]);            // drains A(0)
  {
    short8 a0_ = cvt8(aLo[0], aHi[0]);
    DSWRITE(wtOff, a0_, 0);            // tile 0 -> buf 0
  }
  asm volatile("s_waitcnt lgkmcnt(0)" ::: "memory");
  __builtin_amdgcn_s_barrier();

#pragma unroll
  for (int i = 0; i < 16; ++i) {
    if (i + 1 < 16) LOADB((i + 1) & 1, (t0 + i + 1) & 15);
    if (i + 2 < 16) ALOAD((i + 2) & 1, (t0 + i + 2) & 15);

    // a-frags: one b128 per mt from bf16 tile (buf i&1)
    short8 af0, af1, af2, af3;
    DSREADS(af0, rdOff, ((i & 1) * 4096 + 0 * 1024));
    DSREADS(af1, rdOff, ((i & 1) * 4096 + 1 * 1024));
    DSREADS(af2, rdOff, ((i & 1) * 4096 + 2 * 1024));
    DSREADS(af3, rdOff, ((i & 1) * 4096 + 3 * 1024));
    asm volatile("s_waitcnt lgkmcnt(0)" ::: "memory");
    __builtin_amdgcn_sched_barrier(0);   // rule 18: nothing crosses the lgkm wait

    if (i <= 13)      BWAIT(8, bf[i & 1][0], bf[i & 1][1], bf[i & 1][2], bf[i & 1][3]);
    else if (i == 14) BWAIT(6, bf[i & 1][0], bf[i & 1][1], bf[i & 1][2], bf[i & 1][3]);
    else              BWAIT(0, bf[i & 1][0], bf[i & 1][1], bf[i & 1][2], bf[i & 1][3]);

#pragma unroll
    for (int nt = 0; nt < 4; ++nt) {
      acc[0][nt] = __builtin_amdgcn_mfma_f32_16x16x32_bf16(af0, bf[i & 1][nt], acc[0][nt], 0, 0, 0);
      acc[1][nt] = __builtin_amdgcn_mfma_f32_16x16x32_bf16(af1, bf[i & 1][nt], acc[1][nt], 0, 0, 0);
      acc[2][nt] = __builtin_amdgcn_mfma_f32_16x16x32_bf16(af2, bf[i & 1][nt], acc[2][nt], 0, 0, 0);
      acc[3][nt] = __builtin_amdgcn_mfma_f32_16x16x32_bf16(af3, bf[i & 1][nt], acc[3][nt], 0, 0, 0);
    }

    if (i + 1 < 16) {
      // drain A(i+1), convert once, publish tile(i+1) to the other buffer
      if (i <= 13) AWAIT(6, aLo[(i + 1) & 1], aHi[(i + 1) & 1]);
      else         AWAIT(4, aLo[(i + 1) & 1], aHi[(i + 1) & 1]);
      short8 an_ = cvt8(aLo[(i + 1) & 1], aHi[(i + 1) & 1]);
      DSWRITE(wtOff, an_, (((i + 1) & 1) * 4096));
      asm volatile("s_waitcnt lgkmcnt(0)" ::: "memory");
      __builtin_amdgcn_s_barrier();
    }
  }

  // ---- epilogue: score += v_a * tanh(acc) ----
  float va[4];
#pragma unroll
  for (int nt = 0; nt < 4; ++nt) va[nt] = v_a[n0 + nt * 16 + c];

  float rowsum[4][4];
#pragma unroll
  for (int mt = 0; mt < 4; ++mt) {
#pragma unroll
    for (int r = 0; r < 4; ++r) {
      float sum = 0.f;
#pragma unroll
      for (int nt = 0; nt < 4; ++nt) {
        float x = acc[mt][nt][r];
        float e = __builtin_amdgcn_exp2f(x * 2.8853900817779268f);
        float t = 1.f - 2.f * __builtin_amdgcn_rcpf(e + 1.f);
        sum = fmaf(va[nt], t, sum);
      }
      rowsum[mt][r] = sum;
    }
  }

#pragma unroll
  for (int off = 1; off < 16; off <<= 1) {
#pragma unroll
    for (int mt = 0; mt < 4; ++mt)
#pragma unroll
      for (int r = 0; r < 4; ++r)
        rowsum[mt][r] += __shfl_xor(rowsum[mt][r], off, 64);
  }

  if (c == 0) {
#pragma unroll
    for (int mt = 0; mt < 4; ++mt)
#pragma unroll
      for (int r = 0; r < 4; ++r)
        partial[w * 64 + mt * 16 + q * 4 + r] = rowsum[mt][r];
  }
  __syncthreads();

  if (tid < 64) {
    float sum = 0.f;
#pragma unroll
    for (int ww = 0; ww < 4; ++ww) sum += partial[ww * 64 + tid];
    atomicAdd(&out[(size_t)tid * SEQ + s], sum);   // exactly 2 adds/element (h=0,1)
  }
}

extern "C" void kernel_launch(void* const* d_in, const int* in_sizes, int n_in,
                              void* d_out, int out_size, void* d_ws, size_t ws_size,
                              hipStream_t stream) {
  const float* dec_out = (const float*)d_in[0];   // (64, 512)
  const float* enc     = (const float*)d_in[1];   // (2048, 64, 512)
  const float* W_s     = (const float*)d_in[2];   // (512, 512)
  const float* W_t     = (const float*)d_in[3];   // (512, 512)
  const float* b_t     = (const float*)d_in[4];   // (512,)
  const float* v_a     = (const float*)d_in[5];   // (512,)
  float* out = (float*)d_out;                     // (64, 2048)

  unsigned short* wsb = (unsigned short*)d_ws;                     // 512 KB: W_s bf16 image
  float* decT = (float*)((char*)d_ws + (size_t)ATT * HID * 2);     // 128 KB: dec_att^T fp32

  bahdanau_pre<<<128, 256, 0, stream>>>(dec_out, W_t, b_t, W_s, wsb, decT, out);
  bahdanau_main<<<SEQ * 2, 256, 0, stream>>>(enc, wsb, decT, v_a, out);
}